// Round 3
// baseline (160.732 us; speedup 1.0000x reference)
//
#include <hip/hip_runtime.h>
#include <hip/hip_bf16.h>

#define CC 728
#define PP 364          // pairs (odd/even phase length)
#define KP 384          // padded pair-K: 12 * 32
#define M_ROWS 46208    // 32*38*38 = 361 * 128
#define KT 12
#define NWG 1083        // 361 m-tiles * 3 pair-n tiles

typedef __attribute__((ext_vector_type(8))) short bf16x8;
typedef __attribute__((ext_vector_type(8))) unsigned short ushort8;
typedef __attribute__((ext_vector_type(4))) float f32x4;

// round-to-nearest-even fp32 -> bf16 bits
__device__ __forceinline__ unsigned short f2bf(float f) {
    unsigned int u = __float_as_uint(f);
    unsigned int r = u + 0x7fffu + ((u >> 16) & 1u);
    return (unsigned short)(r >> 16);
}

__device__ __forceinline__ void gload_lds16(const void* g, void* l) {
    __builtin_amdgcn_global_load_lds(
        (const __attribute__((address_space(1))) void*)g,
        (__attribute__((address_space(3))) void*)l,
        16, 0, 0);
}

// h[d] for odd d (validated closed form, rounds 1-2):
//   h[d] = s * cos(pi d/728) / (728 sin(pi d/728)),  s = +1 if (d>>1)&1 else -1
// Bt1[n][k] = h[2*((n-k-1) mod 364)+1]   (Ye = 0.5 E + Bt1 . O)
// Bt2[n][k] = h[2*((n-k)   mod 364)+1]   (Yo = 0.5 O + Bt2 . E)
// Both padded to [384][384] bf16, zero outside n<364 && k<364.
__global__ void build_bt(unsigned short* __restrict__ bt1,
                         unsigned short* __restrict__ bt2) {
    int idx = blockIdx.x * blockDim.x + threadIdx.x;
    if (idx >= 2 * KP * KP) return;
    int mat = idx / (KP * KP);
    int rem = idx % (KP * KP);
    int n = rem / KP, k = rem % KP;
    float v = 0.f;
    if (n < PP && k < PP) {
        int m = n - k - (mat == 0 ? 1 : 0);
        if (m < 0) m += PP;
        int d = 2 * m + 1;
        float t = (float)(3.14159265358979323846 * (double)d / (double)CC);
        float s = ((d >> 1) & 1) ? 1.f : -1.f;
        v = s * cosf(t) / ((float)CC * sinf(t));
    }
    (mat == 0 ? bt1 : bt2)[n * KP + k] = f2bf(v);
}

// Fused even/odd split GEMM:
//   out[r][2n]   = relu(0.5 x[r][2n]   + sum_k Bt1[n][k] * x[r][2k+1])
//   out[r][2n+1] = relu(0.5 x[r][2n+1] + sum_k Bt2[n][k] * x[r][2k])
// 128 rows x 128 pair-cols per block; E/O de-interleaved in registers from
// shared float4 reads; chunk-rotation swizzle on all LDS tiles (round-2
// pattern, 0 conflicts); XCD-bijective wgid swizzle.
__global__ __launch_bounds__(256) void gemm_relu(
        const float* __restrict__ x,
        const unsigned short* __restrict__ bt1,
        const unsigned short* __restrict__ bt2,
        float* __restrict__ out) {
    __shared__ unsigned short ldsE[128 * 32];
    __shared__ unsigned short ldsO[128 * 32];
    __shared__ unsigned short ldsB1[128 * 32];
    __shared__ unsigned short ldsB2[128 * 32];

    const int tid  = threadIdx.x;
    const int lane = tid & 63;
    const int wid  = tid >> 6;
    const int wr   = wid >> 1, wc = wid & 1;
    const int l15  = lane & 15, lhi = lane >> 4;

    // bijective XCD swizzle (m204); consecutive wgids share an A row-panel (3x)
    const int NX = 8;
    int orig = blockIdx.x;
    int q = NWG / NX, r = NWG % NX;          // 135, 3
    int xcd = orig % NX, local = orig / NX;
    int wgid = (xcd < r ? xcd * (q + 1) : r * (q + 1) + (xcd - r) * q) + local;
    const int bm  = (wgid / 3) * 128;
    const int bnp = (wgid % 3) * 128;        // pair-col base

    f32x4 acc_e[4][4], acc_o[4][4];
#pragma unroll
    for (int i = 0; i < 4; ++i)
#pragma unroll
        for (int j = 0; j < 4; ++j)
#pragma unroll
            for (int rr = 0; rr < 4; ++rr) { acc_e[i][j][rr] = 0.f; acc_o[i][j][rr] = 0.f; }

    const int arow = tid >> 1;        // 0..127 (A-staging row)
    const int ah   = tid & 1;         // which 32-channel half of the 64-channel step
    const int brow = tid >> 2;        // B-staging row within 64-row issue
    const int bc   = tid & 3;         // B 8-elem chunk id

    for (int kt = 0; kt < KT; ++kt) {
        const int k0 = kt * 32;       // pair-k base; channels [2k0, 2k0+64)

        // ---- B1/B2: async global->LDS, linear dest, pre-swizzled source chunk ----
#pragma unroll
        for (int i = 0; i < 2; ++i) {
            int rr   = i * 64 + brow;
            int gsrc = (bc - (rr >> 1)) & 3;
            size_t srcoff = (size_t)(bnp + rr) * KP + k0 + gsrc * 8;
            gload_lds16(bt1 + srcoff, &ldsB1[(i * 256 + tid) * 8]);
            gload_lds16(bt2 + srcoff, &ldsB2[(i * 256 + tid) * 8]);
        }

        // ---- A: fp32 global -> regs (8 float4 = 32 ch = 16 pairs) ----
        float4 va[8];
        const int cb0 = 2 * k0 + ah * 32;    // first channel this thread covers
        const float* srcA = x + (size_t)(bm + arow) * CC + cb0;
        const bool full = (cb0 + 32 <= CC);
        if (full) {
#pragma unroll
            for (int i = 0; i < 8; ++i) va[i] = ((const float4*)srcA)[i];
        } else {
#pragma unroll
            for (int i = 0; i < 8; ++i)
                va[i] = (cb0 + 4 * i < CC) ? ((const float4*)srcA)[i]
                                           : make_float4(0.f, 0.f, 0.f, 0.f);
        }

        // ---- de-interleave + cvt + swizzled ds_write (chunks ah*2, ah*2+1) ----
        {
            int rot = (arow >> 1) & 3;
#pragma unroll
            for (int c = 0; c < 2; ++c) {          // two 8-pair chunks
                ushort8 oe, oo;
#pragma unroll
                for (int p = 0; p < 4; ++p) {      // 4 float4 = 8 pairs
                    float4 f = va[c * 4 + p];
                    oe[2 * p]     = f2bf(f.x); oo[2 * p]     = f2bf(f.y);
                    oe[2 * p + 1] = f2bf(f.z); oo[2 * p + 1] = f2bf(f.w);
                }
                int sc = ((ah * 2 + c) + rot) & 3;
                *(ushort8*)&ldsE[(arow * 4 + sc) * 8] = oe;
                *(ushort8*)&ldsO[(arow * 4 + sc) * 8] = oo;
            }
        }
        __syncthreads();   // drains vmcnt (B tiles) + lgkm (A writes)

        // ---- frags + MFMA ----
        bf16x8 aE[4], aO[4], b1[4], b2[4];
#pragma unroll
        for (int mi = 0; mi < 4; ++mi) {
            int row = wr * 64 + mi * 16 + l15;
            int c   = (lhi + (row >> 1)) & 3;
            aE[mi] = *(const bf16x8*)&ldsE[(row * 4 + c) * 8];
            aO[mi] = *(const bf16x8*)&ldsO[(row * 4 + c) * 8];
        }
#pragma unroll
        for (int nj = 0; nj < 4; ++nj) {
            int row = wc * 64 + nj * 16 + l15;
            int c   = (lhi + (row >> 1)) & 3;
            b1[nj] = *(const bf16x8*)&ldsB1[(row * 4 + c) * 8];
            b2[nj] = *(const bf16x8*)&ldsB2[(row * 4 + c) * 8];
        }
#pragma unroll
        for (int mi = 0; mi < 4; ++mi)
#pragma unroll
            for (int nj = 0; nj < 4; ++nj) {
                acc_e[mi][nj] = __builtin_amdgcn_mfma_f32_16x16x32_bf16(
                    aO[mi], b1[nj], acc_e[mi][nj], 0, 0, 0);
                acc_o[mi][nj] = __builtin_amdgcn_mfma_f32_16x16x32_bf16(
                    aE[mi], b2[nj], acc_o[mi][nj], 0, 0, 0);
            }
        __syncthreads();
    }

    // ---- epilogue: +0.5x identity, relu, interleaved float2 store ----
#pragma unroll
    for (int mi = 0; mi < 4; ++mi) {
#pragma unroll
        for (int nj = 0; nj < 4; ++nj) {
            int colp = bnp + wc * 64 + nj * 16 + l15;
            if (colp < PP) {
#pragma unroll
                for (int rr = 0; rr < 4; ++rr) {
                    int rowg = bm + wr * 64 + mi * 16 + lhi * 4 + rr;
                    size_t base = (size_t)rowg * CC + 2 * colp;
                    float2 xv = *(const float2*)&x[base];
                    float2 o;
                    float ye = 0.5f * xv.x + acc_e[mi][nj][rr];
                    float yo = 0.5f * xv.y + acc_o[mi][nj][rr];
                    o.x = ye > 0.f ? ye : 0.f;
                    o.y = yo > 0.f ? yo : 0.f;
                    *(float2*)&out[base] = o;
                }
            }
        }
    }
}

extern "C" void kernel_launch(void* const* d_in, const int* in_sizes, int n_in,
                              void* d_out, int out_size, void* d_ws, size_t ws_size,
                              hipStream_t stream) {
    const float* x = (const float*)d_in[0];
    float* out = (float*)d_out;

    unsigned short* bt1 = (unsigned short*)d_ws;            // 384*384 bf16
    unsigned short* bt2 = bt1 + KP * KP;                    // 384*384 bf16

    build_bt<<<(2 * KP * KP + 255) / 256, 256, 0, stream>>>(bt1, bt2);
    gemm_relu<<<NWG, 256, 0, stream>>>(x, bt1, bt2, out);
}

// Round 4
// 112.584 us; speedup vs baseline: 1.4277x; 1.4277x over previous
//
#include <hip/hip_runtime.h>
#include <hip/hip_bf16.h>

#define CC 728
#define PP 364          // pairs (even/odd phase length)
#define KP 384          // padded pair-K: 12 * 32
#define M_ROWS 46208    // 32*38*38 = 722 * 64
#define KT 12
#define NWG 2166        // 722 m-tiles * 3 pair-n tiles

typedef __attribute__((ext_vector_type(8))) short bf16x8;
typedef __attribute__((ext_vector_type(8))) unsigned short ushort8;
typedef __attribute__((ext_vector_type(4))) float f32x4;

// round-to-nearest-even fp32 -> bf16 bits
__device__ __forceinline__ unsigned short f2bf(float f) {
    unsigned int u = __float_as_uint(f);
    unsigned int r = u + 0x7fffu + ((u >> 16) & 1u);
    return (unsigned short)(r >> 16);
}

__device__ __forceinline__ void gload_lds16(const void* g, void* l) {
    __builtin_amdgcn_global_load_lds(
        (const __attribute__((address_space(1))) void*)g,
        (__attribute__((address_space(3))) void*)l,
        16, 0, 0);
}

// h[d] for odd d (validated closed form, rounds 1-3):
//   h[d] = s * cos(pi d/728) / (728 sin(pi d/728)),  s = +1 if (d>>1)&1 else -1
// Bt1[n][k] = h[2*((n-k-1) mod 364)+1]   (Ye = 0.5 E + Bt1 . O)
// Bt2[n][k] = h[2*((n-k)   mod 364)+1]   (Yo = 0.5 O + Bt2 . E)
// Both padded to [384][384] bf16, zero outside n<364 && k<364.
__global__ void build_bt(unsigned short* __restrict__ bt1,
                         unsigned short* __restrict__ bt2) {
    int idx = blockIdx.x * blockDim.x + threadIdx.x;
    if (idx >= 2 * KP * KP) return;
    int mat = idx / (KP * KP);
    int rem = idx % (KP * KP);
    int n = rem / KP, k = rem % KP;
    float v = 0.f;
    if (n < PP && k < PP) {
        int m = n - k - (mat == 0 ? 1 : 0);
        if (m < 0) m += PP;
        int d = 2 * m + 1;
        float t = (float)(3.14159265358979323846 * (double)d / (double)CC);
        float s = ((d >> 1) & 1) ? 1.f : -1.f;
        v = s * cosf(t) / ((float)CC * sinf(t));
    }
    (mat == 0 ? bt1 : bt2)[n * KP + k] = f2bf(v);
}

// Even/odd split GEMM, 64 rows x 128 pair-cols per block, double-buffered
// 2-phase pipeline (one barrier per K-step, loads overlap MFMA).
//   out[r][2n]   = relu(0.5 x[r][2n]   + sum_k Bt1[n][k] * x[r][2k+1])
//   out[r][2n+1] = relu(0.5 x[r][2n+1] + sum_k Bt2[n][k] * x[r][2k])
__global__ __launch_bounds__(256) void gemm_relu(
        const float* __restrict__ x,
        const unsigned short* __restrict__ bt1,
        const unsigned short* __restrict__ bt2,
        float* __restrict__ out) {
    __shared__ unsigned short ldsE[2][64 * 32];    //  8 KB
    __shared__ unsigned short ldsO[2][64 * 32];    //  8 KB
    __shared__ unsigned short ldsB1[2][128 * 32];  // 16 KB
    __shared__ unsigned short ldsB2[2][128 * 32];  // 16 KB

    const int tid  = threadIdx.x;
    const int lane = tid & 63;
    const int wid  = tid >> 6;
    const int wr   = wid >> 1, wc = wid & 1;       // 2x2 wave grid
    const int l15  = lane & 15, lhi = lane >> 4;

    // bijective XCD swizzle (m204); consecutive wgids share an A row-panel (3x)
    const int NX = 8;
    int orig = blockIdx.x;
    int q = NWG / NX, r = NWG % NX;                // 270, 6
    int xcd = orig % NX, local = orig / NX;
    int wgid = (xcd < r ? xcd * (q + 1) : r * (q + 1) + (xcd - r) * q) + local;
    const int bm  = (wgid / 3) * 64;
    const int bnp = (wgid % 3) * 128;              // pair-col base

    f32x4 acc_e[2][4], acc_o[2][4];
#pragma unroll
    for (int i = 0; i < 2; ++i)
#pragma unroll
        for (int j = 0; j < 4; ++j)
#pragma unroll
            for (int rr = 0; rr < 4; ++rr) { acc_e[i][j][rr] = 0.f; acc_o[i][j][rr] = 0.f; }

    const int brow = tid >> 2;     // B-staging row within 64-row issue
    const int bc   = tid & 3;      // B 8-elem chunk id
    const int arow = tid >> 2;     // A-staging row (0..63)
    const int acx  = tid & 3;      // A 16-channel chunk id

    // ---- staging helpers ----
    auto stageB = [&](int buf, int k0) {
#pragma unroll
        for (int i = 0; i < 2; ++i) {
            int rr   = i * 64 + brow;
            int gsrc = (bc - (rr >> 1)) & 3;
            size_t so = (size_t)(bnp + rr) * KP + k0 + gsrc * 8;
            gload_lds16(bt1 + so, &ldsB1[buf][(i * 256 + tid) * 8]);
            gload_lds16(bt2 + so, &ldsB2[buf][(i * 256 + tid) * 8]);
        }
    };
    auto loadA = [&](int k0, float4* va) {
        int cb0 = 2 * k0 + acx * 16;
        const float* src = x + (size_t)(bm + arow) * CC + cb0;
#pragma unroll
        for (int i = 0; i < 4; ++i)
            va[i] = (cb0 + 4 * i < CC) ? ((const float4*)src)[i]
                                       : make_float4(0.f, 0.f, 0.f, 0.f);
    };
    auto writeA = [&](int buf, const float4* va) {
        ushort8 oe, oo;
#pragma unroll
        for (int p = 0; p < 4; ++p) {
            float4 f = va[p];
            oe[2 * p]     = f2bf(f.x); oo[2 * p]     = f2bf(f.y);
            oe[2 * p + 1] = f2bf(f.z); oo[2 * p + 1] = f2bf(f.w);
        }
        int sc = (acx + (arow >> 1)) & 3;
        *(ushort8*)&ldsE[buf][arow * 32 + sc * 8] = oe;
        *(ushort8*)&ldsO[buf][arow * 32 + sc * 8] = oo;
    };

    // ---- prologue: fill buffer 0 ----
    {
        float4 va[4];
        stageB(0, 0);
        loadA(0, va);
        writeA(0, va);
    }
    __syncthreads();

    int cur = 0;
    for (int kt = 0; kt < KT; ++kt) {
        const int nxt = cur ^ 1;
        const bool more = (kt + 1 < KT);

        // issue next-tile loads first (overlap with MFMA below)
        float4 va2[4];
        if (more) {
            stageB(nxt, (kt + 1) * 32);
            loadA((kt + 1) * 32, va2);
        }

        // ---- frags + MFMA on current buffer ----
        bf16x8 aE[2], aO[2], b1[4], b2[4];
#pragma unroll
        for (int mi = 0; mi < 2; ++mi) {
            int row = wr * 32 + mi * 16 + l15;
            int c   = (lhi + (row >> 1)) & 3;
            aE[mi] = *(const bf16x8*)&ldsE[cur][row * 32 + c * 8];
            aO[mi] = *(const bf16x8*)&ldsO[cur][row * 32 + c * 8];
        }
#pragma unroll
        for (int nj = 0; nj < 4; ++nj) {
            int row = wc * 64 + nj * 16 + l15;
            int c   = (lhi + (row >> 1)) & 3;
            b1[nj] = *(const bf16x8*)&ldsB1[cur][row * 32 + c * 8];
            b2[nj] = *(const bf16x8*)&ldsB2[cur][row * 32 + c * 8];
        }
#pragma unroll
        for (int mi = 0; mi < 2; ++mi)
#pragma unroll
            for (int nj = 0; nj < 4; ++nj) {
                acc_e[mi][nj] = __builtin_amdgcn_mfma_f32_16x16x32_bf16(
                    aO[mi], b1[nj], acc_e[mi][nj], 0, 0, 0);
                acc_o[mi][nj] = __builtin_amdgcn_mfma_f32_16x16x32_bf16(
                    aE[mi], b2[nj], acc_o[mi][nj], 0, 0, 0);
            }

        // write next A tile (loads arrived during MFMA)
        if (more) writeA(nxt, va2);

        __syncthreads();   // single drain+barrier per K-step
        cur = nxt;
    }

    // ---- epilogue: +0.5x identity, relu, interleaved float2 store ----
#pragma unroll
    for (int mi = 0; mi < 2; ++mi) {
#pragma unroll
        for (int nj = 0; nj < 4; ++nj) {
            int colp = bnp + wc * 64 + nj * 16 + l15;
            if (colp < PP) {
#pragma unroll
                for (int rr = 0; rr < 4; ++rr) {
                    int rowg = bm + wr * 32 + mi * 16 + lhi * 4 + rr;
                    size_t base = (size_t)rowg * CC + 2 * colp;
                    float2 xv = *(const float2*)&x[base];
                    float2 o;
                    float ye = 0.5f * xv.x + acc_e[mi][nj][rr];
                    float yo = 0.5f * xv.y + acc_o[mi][nj][rr];
                    o.x = ye > 0.f ? ye : 0.f;
                    o.y = yo > 0.f ? yo : 0.f;
                    *(float2*)&out[base] = o;
                }
            }
        }
    }
}

extern "C" void kernel_launch(void* const* d_in, const int* in_sizes, int n_in,
                              void* d_out, int out_size, void* d_ws, size_t ws_size,
                              hipStream_t stream) {
    const float* x = (const float*)d_in[0];
    float* out = (float*)d_out;

    unsigned short* bt1 = (unsigned short*)d_ws;            // 384*384 bf16
    unsigned short* bt2 = bt1 + KP * KP;                    // 384*384 bf16

    build_bt<<<(2 * KP * KP + 255) / 256, 256, 0, stream>>>(bt1, bt2);
    gemm_relu<<<NWG, 256, 0, stream>>>(x, bt1, bt2, out);
}

// Round 5
// 108.869 us; speedup vs baseline: 1.4764x; 1.0341x over previous
//
#include <hip/hip_runtime.h>
#include <hip/hip_bf16.h>

#define CC 728
#define PP 364          // pairs (even/odd phase length)
#define KP 384          // padded pair-K: 12 * 32
#define M_ROWS 46208    // 32*38*38 = 722 * 64
#define KT 12
#define NWG 2166        // 722 m-tiles * 3 pair-n tiles

typedef __attribute__((ext_vector_type(8))) short bf16x8;
typedef __attribute__((ext_vector_type(8))) unsigned short ushort8;
typedef __attribute__((ext_vector_type(4))) float f32x4;

// round-to-nearest-even fp32 -> bf16 bits
__device__ __forceinline__ unsigned short f2bf(float f) {
    unsigned int u = __float_as_uint(f);
    unsigned int r = u + 0x7fffu + ((u >> 16) & 1u);
    return (unsigned short)(r >> 16);
}

__device__ __forceinline__ void gload_lds16(const void* g, void* l) {
    __builtin_amdgcn_global_load_lds(
        (const __attribute__((address_space(1))) void*)g,
        (__attribute__((address_space(3))) void*)l,
        16, 0, 0);
}

// h[d] for odd d (validated closed form, rounds 1-4):
//   h[d] = s * cos(pi d/728) / (728 sin(pi d/728)),  s = +1 if (d>>1)&1 else -1
// Bt1[n][k] = h[2*((n-k-1) mod 364)+1]   (Ye = 0.5 E + Bt1 . O)
// Bt2[n][k] = h[2*((n-k)   mod 364)+1]   (Yo = 0.5 O + Bt2 . E)
// Both padded to [384][384] bf16, zero outside n<364 && k<364.
__global__ void build_bt(unsigned short* __restrict__ bt1,
                         unsigned short* __restrict__ bt2) {
    int idx = blockIdx.x * blockDim.x + threadIdx.x;
    if (idx >= 2 * KP * KP) return;
    int mat = idx / (KP * KP);
    int rem = idx % (KP * KP);
    int n = rem / KP, k = rem % KP;
    float v = 0.f;
    if (n < PP && k < PP) {
        int m = n - k - (mat == 0 ? 1 : 0);
        if (m < 0) m += PP;
        int d = 2 * m + 1;
        float t = (float)(3.14159265358979323846 * (double)d / (double)CC);
        float s = ((d >> 1) & 1) ? 1.f : -1.f;
        v = s * cosf(t) / ((float)CC * sinf(t));
    }
    (mat == 0 ? bt1 : bt2)[n * KP + k] = f2bf(v);
}

// Even/odd split GEMM, 64 rows x 128 pair-cols per block.
// Round-2 proven schedule: SINGLE-buffered 24KB LDS, 2 barriers per K-step,
// latency hidden by block-level TLP (~5 blocks/CU), not explicit pipelining.
//   out[r][2n]   = relu(0.5 x[r][2n]   + sum_k Bt1[n][k] * x[r][2k+1])
//   out[r][2n+1] = relu(0.5 x[r][2n+1] + sum_k Bt2[n][k] * x[r][2k])
__global__ __launch_bounds__(256) void gemm_relu(
        const float* __restrict__ x,
        const unsigned short* __restrict__ bt1,
        const unsigned short* __restrict__ bt2,
        float* __restrict__ out) {
    __shared__ unsigned short ldsE[64 * 32];     // 4 KB
    __shared__ unsigned short ldsO[64 * 32];     // 4 KB
    __shared__ unsigned short ldsB1[128 * 32];   // 8 KB
    __shared__ unsigned short ldsB2[128 * 32];   // 8 KB

    const int tid  = threadIdx.x;
    const int lane = tid & 63;
    const int wid  = tid >> 6;
    const int wr   = wid >> 1, wc = wid & 1;     // 2x2 wave grid
    const int l15  = lane & 15, lhi = lane >> 4;

    // bijective XCD swizzle (m204); consecutive wgids share an A row-panel (3x)
    const int NX = 8;
    int orig = blockIdx.x;
    int q = NWG / NX, r = NWG % NX;              // 270, 6
    int xcd = orig % NX, local = orig / NX;
    int wgid = (xcd < r ? xcd * (q + 1) : r * (q + 1) + (xcd - r) * q) + local;
    const int bm  = (wgid / 3) * 64;
    const int bnp = (wgid % 3) * 128;            // pair-col base

    f32x4 acc_e[2][4], acc_o[2][4];
#pragma unroll
    for (int i = 0; i < 2; ++i)
#pragma unroll
        for (int j = 0; j < 4; ++j)
#pragma unroll
            for (int rr = 0; rr < 4; ++rr) { acc_e[i][j][rr] = 0.f; acc_o[i][j][rr] = 0.f; }

    const int brow = tid >> 2;     // B-staging row within 64-row issue
    const int bc   = tid & 3;      // B 8-elem chunk id
    const int arow = tid >> 2;     // A-staging row (0..63)
    const int acx  = tid & 3;      // A 16-channel chunk id

    for (int kt = 0; kt < KT; ++kt) {
        const int k0 = kt * 32;    // pair-k base; channels [2k0, 2k0+64)

        // ---- B1/B2: async global->LDS, linear dest, pre-swizzled source ----
#pragma unroll
        for (int i = 0; i < 2; ++i) {
            int rr   = i * 64 + brow;
            int gsrc = (bc - (rr >> 1)) & 3;
            size_t so = (size_t)(bnp + rr) * KP + k0 + gsrc * 8;
            gload_lds16(bt1 + so, &ldsB1[(i * 256 + tid) * 8]);
            gload_lds16(bt2 + so, &ldsB2[(i * 256 + tid) * 8]);
        }

        // ---- A: fp32 global -> regs (4 float4 = 16 ch = 8 pairs) ----
        float4 va[4];
        {
            int cb0 = 2 * k0 + acx * 16;
            const float* src = x + (size_t)(bm + arow) * CC + cb0;
#pragma unroll
            for (int i = 0; i < 4; ++i)
                va[i] = (cb0 + 4 * i < CC) ? ((const float4*)src)[i]
                                           : make_float4(0.f, 0.f, 0.f, 0.f);
        }

        // ---- de-interleave + cvt + swizzled ds_write ----
        {
            ushort8 oe, oo;
#pragma unroll
            for (int p = 0; p < 4; ++p) {
                float4 f = va[p];
                oe[2 * p]     = f2bf(f.x); oo[2 * p]     = f2bf(f.y);
                oe[2 * p + 1] = f2bf(f.z); oo[2 * p + 1] = f2bf(f.w);
            }
            int sc = (acx + (arow >> 1)) & 3;
            *(ushort8*)&ldsE[arow * 32 + sc * 8] = oe;
            *(ushort8*)&ldsO[arow * 32 + sc * 8] = oo;
        }
        __syncthreads();   // drains vmcnt (B DMA) + lgkm (A writes)

        // ---- frags + MFMA ----
        bf16x8 aE[2], aO[2], b1[4], b2[4];
#pragma unroll
        for (int mi = 0; mi < 2; ++mi) {
            int row = wr * 32 + mi * 16 + l15;
            int c   = (lhi + (row >> 1)) & 3;
            aE[mi] = *(const bf16x8*)&ldsE[row * 32 + c * 8];
            aO[mi] = *(const bf16x8*)&ldsO[row * 32 + c * 8];
        }
#pragma unroll
        for (int nj = 0; nj < 4; ++nj) {
            int row = wc * 64 + nj * 16 + l15;
            int c   = (lhi + (row >> 1)) & 3;
            b1[nj] = *(const bf16x8*)&ldsB1[row * 32 + c * 8];
            b2[nj] = *(const bf16x8*)&ldsB2[row * 32 + c * 8];
        }
#pragma unroll
        for (int mi = 0; mi < 2; ++mi)
#pragma unroll
            for (int nj = 0; nj < 4; ++nj) {
                acc_e[mi][nj] = __builtin_amdgcn_mfma_f32_16x16x32_bf16(
                    aO[mi], b1[nj], acc_e[mi][nj], 0, 0, 0);
                acc_o[mi][nj] = __builtin_amdgcn_mfma_f32_16x16x32_bf16(
                    aE[mi], b2[nj], acc_o[mi][nj], 0, 0, 0);
            }
        __syncthreads();   // protect single-buffered LDS for next step
    }

    // ---- epilogue: +0.5x identity, relu, interleaved float2 store ----
#pragma unroll
    for (int mi = 0; mi < 2; ++mi) {
#pragma unroll
        for (int nj = 0; nj < 4; ++nj) {
            int colp = bnp + wc * 64 + nj * 16 + l15;
            if (colp < PP) {
#pragma unroll
                for (int rr = 0; rr < 4; ++rr) {
                    int rowg = bm + wr * 32 + mi * 16 + lhi * 4 + rr;
                    size_t base = (size_t)rowg * CC + 2 * colp;
                    float2 xv = *(const float2*)&x[base];
                    float2 o;
                    float ye = 0.5f * xv.x + acc_e[mi][nj][rr];
                    float yo = 0.5f * xv.y + acc_o[mi][nj][rr];
                    o.x = ye > 0.f ? ye : 0.f;
                    o.y = yo > 0.f ? yo : 0.f;
                    *(float2*)&out[base] = o;
                }
            }
        }
    }
}

extern "C" void kernel_launch(void* const* d_in, const int* in_sizes, int n_in,
                              void* d_out, int out_size, void* d_ws, size_t ws_size,
                              hipStream_t stream) {
    const float* x = (const float*)d_in[0];
    float* out = (float*)d_out;

    unsigned short* bt1 = (unsigned short*)d_ws;            // 384*384 bf16
    unsigned short* bt2 = bt1 + KP * KP;                    // 384*384 bf16

    build_bt<<<(2 * KP * KP + 255) / 256, 256, 0, stream>>>(bt1, bt2);
    gemm_relu<<<NWG, 256, 0, stream>>>(x, bt1, bt2, out);
}